// Round 1
// baseline (896.660 us; speedup 1.0000x reference)
//
#include <hip/hip_runtime.h>
#include <math.h>

// Merton jump diffusion path simulation.
// out[p][0] = S0; out[p][s+1] = S0 * exp( sum_{k<=s} log_ret[k][p] )
// log_ret[k][p] = -(lam(t_k)*KAPPA)*DT + SIGMA*sqrt(DT)*z_diff[k][p]
//                + sqrt(n_jumps[k][p])*SIGMA_J*z_jump[k][p]
//
// Memory-bound: 768 MiB read + 256 MiB write => ~163 us roofline @ 6.3 TB/s.
// One thread per path, double-buffered register batches (U=16 steps) for MLP.

#define N_STEPS 2048
#define N_PATHS 32768
#define UROLL 16

#define DT_F 0.00048828125f            // 1/2048 exact
#define C_DIFF_F (0.2f * 0.022097086912079608f)  // SIGMA * sqrt(DT)
#define KAPPA_F 0.04602785990871629f   // exp(0.045) - 1
#define SIGMA_J_F 0.3f

__device__ __forceinline__ void load_batch(const float* __restrict__ zd_p,
                                           const float* __restrict__ zj_p,
                                           const int* __restrict__ nj_p,
                                           int base, float* zd, float* zj, int* nj) {
#pragma unroll
    for (int i = 0; i < UROLL; ++i) {
        int off = (base + i) * N_PATHS;   // max 2047*32768 < 2^31/4, int ok
        zd[i] = zd_p[off];
        zj[i] = zj_p[off];
        nj[i] = nj_p[off];
    }
}

__device__ __forceinline__ float compute_batch(int base, const float* zd, const float* zj,
                                               const int* nj, float acc, float s0,
                                               float* __restrict__ out_p) {
#pragma unroll
    for (int i = 0; i < UROLL; ++i) {
        int s = base + i;
        float t = (float)s * DT_F;
        float lam = 0.1f + 0.9f * __expf(-0.01f * t);
        float drift = -(lam * KAPPA_F) * DT_F;
        float njf = (float)nj[i];
        float val = (drift + C_DIFF_F * zd[i]) + sqrtf(njf) * SIGMA_J_F * zj[i];
        acc += val;                       // same fp32 sequential order as jnp.cumsum
        out_p[s] = s0 * __expf(acc);
    }
    return acc;
}

__global__ __launch_bounds__(64) void merton_paths_kernel(
    const float* __restrict__ S0,
    const float* __restrict__ z_diff,
    const float* __restrict__ z_jump,
    const int* __restrict__ n_jumps,
    float* __restrict__ out) {
    const int p = blockIdx.x * blockDim.x + threadIdx.x;   // path index
    const float s0 = S0[0];

    const float* zd_p = z_diff + p;
    const float* zj_p = z_jump + p;
    const int* nj_p = n_jumps + p;
    float* out_p = out + (long)p * (N_STEPS + 1);

    out_p[0] = s0;
    float* out1 = out_p + 1;

    float zdA[UROLL], zjA[UROLL]; int njA[UROLL];
    float zdB[UROLL], zjB[UROLL]; int njB[UROLL];

    float acc = 0.0f;

    // prefetch batch 0
    load_batch(zd_p, zj_p, nj_p, 0, zdA, zjA, njA);

    // outer loop unrolled by 2 batches so buffer choice is compile-time
    for (int base = 0; base < N_STEPS; base += 2 * UROLL) {
        // prefetch B (base+U) — always in range (last base=2016, 2032<2048)
        load_batch(zd_p, zj_p, nj_p, base + UROLL, zdB, zjB, njB);
        acc = compute_batch(base, zdA, zjA, njA, acc, s0, out1);
        // prefetch A (base+2U) — out of range only on the final iteration
        if (base + 2 * UROLL < N_STEPS)
            load_batch(zd_p, zj_p, nj_p, base + 2 * UROLL, zdA, zjA, njA);
        acc = compute_batch(base + UROLL, zdB, zjB, njB, acc, s0, out1);
    }
}

extern "C" void kernel_launch(void* const* d_in, const int* in_sizes, int n_in,
                              void* d_out, int out_size, void* d_ws, size_t ws_size,
                              hipStream_t stream) {
    const float* S0      = (const float*)d_in[0];
    const float* z_diff  = (const float*)d_in[1];
    const float* z_jump  = (const float*)d_in[2];
    const int*   n_jumps = (const int*)d_in[3];
    float* out = (float*)d_out;

    dim3 block(64);
    dim3 grid(N_PATHS / 64);   // 512 blocks -> 2 waves/CU
    hipLaunchKernelGGL(merton_paths_kernel, grid, block, 0, stream,
                       S0, z_diff, z_jump, n_jumps, out);
}

// Round 2
// 877.175 us; speedup vs baseline: 1.0222x; 1.0222x over previous
//
#include <hip/hip_runtime.h>
#include <math.h>

// Merton jump diffusion path simulation.
// out[p][0] = S0; out[p][s+1] = S0 * exp( sum_{k<=s} log_ret[k][p] )
//
// R2: stores were the bottleneck (uncoalesced 64-line scatter per store inst).
// Stage a 64-path x 64-step tile in LDS, drain with coalesced 256B stores.
// Also: incremental exp for lambda(t) (1 transcendental/step saved).

#define N_STEPS 2048
#define N_PATHS 32768
#define U 16
#define TILE_S 64
#define ROW (N_STEPS + 1)

#define DT_F 0.00048828125f                       // 1/2048 exact
#define C_DIFF_F 0.004419417382415922f            // SIGMA * sqrt(DT)
#define KAPPA_F 0.046027859908717f                // exp(0.045) - 1

__device__ __forceinline__ void load_batch(const float* __restrict__ zd_p,
                                           const float* __restrict__ zj_p,
                                           const int* __restrict__ nj_p,
                                           int base, float* zd, float* zj, int* nj) {
#pragma unroll
    for (int i = 0; i < U; ++i) {
        int off = (base + i) * N_PATHS;   // max < 2^26, int ok
        zd[i] = zd_p[off];
        zj[i] = zj_p[off];
        nj[i] = nj_p[off];
    }
}

__device__ __forceinline__ void compute_batch(int jbase, const float* zd, const float* zj,
                                              const int* nj, float& acc, float& e,
                                              float r, float s0,
                                              float* __restrict__ smem_row) {
#pragma unroll
    for (int i = 0; i < U; ++i) {
        float lam = 0.1f + 0.9f * e;
        e *= r;                                    // e = exp(-0.01 * s * DT), incremental
        float drift = -(lam * KAPPA_F) * DT_F;
        float njf = (float)nj[i];
        float val = (drift + C_DIFF_F * zd[i]) + sqrtf(njf) * 0.3f * zj[i];
        acc += val;                                // fp32 sequential, matches cumsum order
        smem_row[jbase + i] = s0 * __expf(acc);
    }
}

__global__ __launch_bounds__(64) void merton_paths_kernel(
    const float* __restrict__ S0,
    const float* __restrict__ z_diff,
    const float* __restrict__ z_jump,
    const int* __restrict__ n_jumps,
    float* __restrict__ out) {
    const int lane = threadIdx.x;
    const int pbase = blockIdx.x * 64;
    const int p = pbase + lane;
    const float s0 = S0[0];

    // 64 paths x 64 steps staging tile; stride 65 words -> 2-way bank alias (free)
    __shared__ float smem[64][TILE_S + 1];

    const float* zd_p = z_diff + p;
    const float* zj_p = z_jump + p;
    const int* nj_p = n_jumps + p;

    out[(long)p * ROW] = s0;

    float zdA[U], zjA[U]; int njA[U];
    float zdB[U], zjB[U]; int njB[U];

    float acc = 0.0f;
    float e = 1.0f;
    const float r = __expf(-0.01f * DT_F);

    load_batch(zd_p, zj_p, nj_p, 0, zdA, zjA, njA);

    for (int tb = 0; tb < N_STEPS; tb += TILE_S) {
        load_batch(zd_p, zj_p, nj_p, tb + U, zdB, zjB, njB);
        compute_batch(0, zdA, zjA, njA, acc, e, r, s0, smem[lane]);
        load_batch(zd_p, zj_p, nj_p, tb + 2 * U, zdA, zjA, njA);
        compute_batch(U, zdB, zjB, njB, acc, e, r, s0, smem[lane]);
        load_batch(zd_p, zj_p, nj_p, tb + 3 * U, zdB, zjB, njB);
        compute_batch(2 * U, zdA, zjA, njA, acc, e, r, s0, smem[lane]);
        if (tb + TILE_S < N_STEPS)
            load_batch(zd_p, zj_p, nj_p, tb + TILE_S, zdA, zjA, njA);
        compute_batch(3 * U, zdB, zjB, njB, acc, e, r, s0, smem[lane]);

        __syncthreads();
        // drain tile: lanes cover consecutive steps for one path -> 256B coalesced
        float* orow = out + (long)pbase * ROW + 1 + tb + lane;
#pragma unroll 16
        for (int rr = 0; rr < 64; ++rr) {
            *orow = smem[rr][lane];
            orow += ROW;
        }
        __syncthreads();
    }
}

extern "C" void kernel_launch(void* const* d_in, const int* in_sizes, int n_in,
                              void* d_out, int out_size, void* d_ws, size_t ws_size,
                              hipStream_t stream) {
    const float* S0      = (const float*)d_in[0];
    const float* z_diff  = (const float*)d_in[1];
    const float* z_jump  = (const float*)d_in[2];
    const int*   n_jumps = (const int*)d_in[3];
    float* out = (float*)d_out;

    dim3 block(64);
    dim3 grid(N_PATHS / 64);   // 512 blocks, 1 wave each -> 2 waves/CU
    hipLaunchKernelGGL(merton_paths_kernel, grid, block, 0, stream,
                       S0, z_diff, z_jump, n_jumps, out);
}